// Round 16
// baseline (128.044 us; speedup 1.0000x reference)
//
#include <hip/hip_runtime.h>

#define T_ 1024
#define D_ 1024
#define B_ 4
#define H_ 16
#define DH_ 64
#define M_ (B_*T_)                 // 4096
#define NEG_ (-4294967295.0f)

typedef __attribute__((ext_vector_type(8))) _Float16 f16x8;
typedef __attribute__((ext_vector_type(4))) float f32x4;

__device__ __forceinline__ unsigned short f2h(float f) {
    _Float16 h = (_Float16)f; unsigned short u; __builtin_memcpy(&u, &h, 2); return u;
}
__device__ __forceinline__ float h2f(unsigned short u) {
    _Float16 h; __builtin_memcpy(&h, &u, 2); return (float)h;
}

typedef const unsigned int __attribute__((address_space(1)))* gas_p;
typedef unsigned int __attribute__((address_space(3)))* las_p;
__device__ __forceinline__ void gl_lds16(const void* g, void* l) {
    __builtin_amdgcn_global_load_lds((gas_p)g, (las_p)l, 16, 0, 0);
}

// ================= fused conversions (one launch) =================
__global__ __launch_bounds__(256) void conv_all(const float* __restrict__ q,
                                                const float* __restrict__ peq,
                                                const float* __restrict__ pek,
                                                const float* __restrict__ Wq,
                                                const float* __restrict__ Wk,
                                                const float* __restrict__ Wv,
                                                const float* __restrict__ fw1,
                                                const int* __restrict__ klv,
                                                unsigned short* __restrict__ A2,
                                                unsigned short* __restrict__ B2,
                                                unsigned short* __restrict__ WvT,
                                                unsigned short* __restrict__ fw1T)
{
    int blk = blockIdx.x;
    if (blk < 8192) {
        int i = blk * 256 + threadIdx.x;
        int m = i >> 8, c4 = (i & 255) << 2;
        int mq = m & 4095;
        if (m >= 4096) {
            int row = m - 4096;
            int kl = klv[row >> 10];
            if (kl > 1 && (row & 1023) >= kl) return;   // dead k_in row
        }
        float4 qv = *(const float4*)(q + (size_t)mq * D_ + c4);
        float4 p  = *(const float4*)(peq + (size_t)(m & (T_-1)) * D_ + c4);
        ushort4 h;
        if (m < 4096) {
            h.x = f2h(qv.x + 32.f*p.x); h.y = f2h(qv.y + 32.f*p.y);
            h.z = f2h(qv.z + 32.f*p.z); h.w = f2h(qv.w + 32.f*p.w);
        } else {
            float4 pk = *(const float4*)(pek + (size_t)(m & (T_-1)) * D_ + c4);
            h.x = f2h(qv.x + 32.f*(p.x + pk.x)); h.y = f2h(qv.y + 32.f*(p.y + pk.y));
            h.z = f2h(qv.z + 32.f*(p.z + pk.z)); h.w = f2h(qv.w + 32.f*(p.w + pk.w));
        }
        *(ushort4*)(A2 + (size_t)m * 1024 + c4) = h;
        return;
    }
    __shared__ float t[32][33];
    int r = threadIdx.x >> 5, c = threadIdx.x & 31;
    if (blk < 10240) {              // conv_w2
        int l = blk - 8192;
        int z = l >> 10, k0 = ((l >> 5) & 31) * 32, n0 = (l & 31) * 32;
        const float* W = z ? Wk : Wq;
        #pragma unroll
        for (int rr = 0; rr < 4; ++rr)
            t[r + 8*rr][c] = W[(size_t)(k0 + r + 8*rr) * 1024 + n0 + c];
        __syncthreads();
        #pragma unroll
        for (int rr = 0; rr < 4; ++rr)
            B2[(size_t)(z * 1024 + n0 + r + 8*rr) * 1024 + k0 + c] = f2h(t[c][r + 8*rr]);
    } else if (blk < 11264) {       // conv_wT(Wv)
        int l = blk - 10240;
        int k0 = (l >> 5) * 32, n0 = (l & 31) * 32;
        #pragma unroll
        for (int rr = 0; rr < 4; ++rr)
            t[r + 8*rr][c] = Wv[(size_t)(k0 + r + 8*rr) * 1024 + n0 + c];
        __syncthreads();
        #pragma unroll
        for (int rr = 0; rr < 4; ++rr)
            WvT[(size_t)(n0 + r + 8*rr) * 1024 + k0 + c] = f2h(t[c][r + 8*rr]);
    } else {                        // conv_wT(fw1)
        int l = blk - 11264;
        int k0 = (l >> 7) * 32, n0 = (l & 127) * 32;
        #pragma unroll
        for (int rr = 0; rr < 4; ++rr)
            t[r + 8*rr][c] = fw1[(size_t)(k0 + r + 8*rr) * 4096 + n0 + c];
        __syncthreads();
        #pragma unroll
        for (int rr = 0; rr < 4; ++rr)
            fw1T[(size_t)(n0 + r + 8*rr) * 1024 + k0 + c] = f2h(t[c][r + 8*rr]);
    }
}

// ======== QK: 256x256 8-wave interleaved-phase GEMM (ffn1_8p skeleton) ========
// [Qh|Kh16] = A2[8192][1024] @ B2[2048][1024]^T, 256-granular length skips.
__global__ __launch_bounds__(512, 2) void qk_8p(
    const unsigned short* __restrict__ A,
    const unsigned short* __restrict__ B,
    unsigned short* __restrict__ Qh, unsigned short* __restrict__ Kh16,
    const int* __restrict__ qlv, const int* __restrict__ klv)
{
    __shared__ __align__(16) unsigned short As[2][16384];
    __shared__ __align__(16) unsigned short Bs[2][16384];
    const int tid = threadIdx.x;
    const int m0 = blockIdx.y << 8, n0 = blockIdx.x << 8;
    if (m0 < 4096) {                               // q_in rows -> Q cols only
        if (n0 >= 1024) return;
        if ((m0 & 1023) >= qlv[m0 >> 10]) return;
    } else {                                       // k_in rows -> K cols only
        if (n0 < 1024) return;
        int kl = klv[(m0 - 4096) >> 10];
        if (kl > 1 && (m0 & 1023) >= kl) return;
    }
    const int lane = tid & 63, wave = tid >> 6;
    const int wm = wave >> 2, wn = wave & 3;
    const int rl = lane & 15, kg = lane >> 4, rl7 = lane & 7;

    const int row0 = tid >> 3;
    const int k8c = (tid & 7) ^ (row0 & 7);
    const int cs0 = tid * 8;
    const int gofs = row0 * 1024 + k8c * 8;
    const unsigned short* Ap = A + (size_t)m0 * 1024 + gofs;
    const unsigned short* Bp = B + (size_t)n0 * 1024 + gofs;

    const int base_a = ((wm * 128 + rl) * 8 + (kg ^ rl7)) * 8;
    const int base_b = (((wn >> 1) * 128 + (wn & 1) * 64 + rl) * 8 + (kg ^ rl7)) * 8;

    f32x4 acc[8][4];
    #pragma unroll
    for (int i = 0; i < 8; ++i)
        #pragma unroll
        for (int j = 0; j < 4; ++j) {
            acc[i][j][0] = 0.f; acc[i][j][1] = 0.f;
            acc[i][j][2] = 0.f; acc[i][j][3] = 0.f;
        }

    const int NT = 16;
    #pragma unroll
    for (int i = 0; i < 4; ++i) gl_lds16(Ap + i * 65536, &As[0][cs0 + i * 4096]);
    #pragma unroll
    for (int i = 0; i < 4; ++i) gl_lds16(Bp + i * 65536, &Bs[0][cs0 + i * 4096]);
    #pragma unroll
    for (int i = 0; i < 4; ++i) gl_lds16(Ap + i * 65536 + 64, &As[1][cs0 + i * 4096]);
    #pragma unroll
    for (int i = 0; i < 4; ++i) gl_lds16(Bp + i * 65536 + 64, &Bs[1][cs0 + i * 4096]);

    for (int t = 0; t < NT; ++t) {
        const int cur = t & 1;
        if (t + 1 < NT) asm volatile("s_waitcnt vmcnt(8)" ::: "memory");
        else            asm volatile("s_waitcnt vmcnt(0)" ::: "memory");
        __builtin_amdgcn_s_barrier();
        __builtin_amdgcn_sched_barrier(0);
        f16x8 av[8][2], bv[4][2];
        #pragma unroll
        for (int f = 0; f < 8; ++f) {
            int o = base_a + f * 1024;
            av[f][0] = *(const f16x8*)&As[cur][o];
            av[f][1] = *(const f16x8*)&As[cur][o ^ 32];
        }
        #pragma unroll
        for (int fn = 0; fn < 4; ++fn) {
            int o = base_b + fn * 1024;
            bv[fn][0] = *(const f16x8*)&Bs[cur][o];
            bv[fn][1] = *(const f16x8*)&Bs[cur][o ^ 32];
        }
        asm volatile("s_waitcnt lgkmcnt(0)" ::: "memory");
        __builtin_amdgcn_sched_barrier(0);
        __builtin_amdgcn_s_barrier();
        __builtin_amdgcn_sched_barrier(0);
        const bool pre = (t + 2 < NT);
        const int ko = (t + 2) << 6;
        #pragma unroll
        for (int p = 0; p < 4; ++p) {
            if (pre) {
                if (p < 2) {
                    gl_lds16(Ap + (2*p) * 65536 + ko,     &As[cur][cs0 + (2*p) * 4096]);
                    gl_lds16(Ap + (2*p + 1) * 65536 + ko, &As[cur][cs0 + (2*p + 1) * 4096]);
                } else {
                    gl_lds16(Bp + (2*p - 4) * 65536 + ko, &Bs[cur][cs0 + (2*p - 4) * 4096]);
                    gl_lds16(Bp + (2*p - 3) * 65536 + ko, &Bs[cur][cs0 + (2*p - 3) * 4096]);
                }
            }
            __builtin_amdgcn_sched_barrier(0);
            __builtin_amdgcn_s_setprio(1);
            #pragma unroll
            for (int f = 2 * p; f < 2 * p + 2; ++f)
                #pragma unroll
                for (int fn = 0; fn < 4; ++fn) {
                    acc[f][fn] = __builtin_amdgcn_mfma_f32_16x16x32_f16(av[f][0], bv[fn][0], acc[f][fn], 0, 0, 0);
                    acc[f][fn] = __builtin_amdgcn_mfma_f32_16x16x32_f16(av[f][1], bv[fn][1], acc[f][fn], 0, 0, 0);
                }
            __builtin_amdgcn_s_setprio(0);
            __builtin_amdgcn_sched_barrier(0);
        }
    }

    // epilogue: row = m0+wm*128+f*16+kg*4+r, col = n0+wn*64+fn*16+rl
    const bool isQ = (m0 < 4096);
    #pragma unroll
    for (int f = 0; f < 8; ++f) {
        int row = m0 + wm * 128 + f * 16 + (kg << 2);
        #pragma unroll
        for (int fn = 0; fn < 4; ++fn) {
            int col = n0 + wn * 64 + fn * 16 + rl;
            #pragma unroll
            for (int r = 0; r < 4; ++r) {
                unsigned short val = f2h(acc[f][fn][r]);
                if (isQ) Qh[(size_t)(row + r) * 1024 + col] = val;
                else     Kh16[(size_t)(row + r - 4096) * 1024 + (col - 1024)] = val;
            }
        }
    }
}

// ======== V GEMM: counted-vmcnt pipelined fp16 MFMA, BM=64/BK=64 (proven) ========
__global__ __launch_bounds__(256) void gemm_v(
    const unsigned short* __restrict__ A,     // Kh16 [4096][1024]
    const unsigned short* __restrict__ B,     // WvT [1024][1024]
    unsigned short* __restrict__ Vt,          // [64 bh][64 dh][1024 t]
    const int* __restrict__ klv)
{
    constexpr int BM = 64, WN = 4, FN = 2, NA = 2;
    __shared__ __align__(16) unsigned short As[2][BM * 64];
    __shared__ __align__(16) unsigned short Bs[2][128 * 64];
    const int tid = threadIdx.x;
    const int m0 = blockIdx.y * BM, n0 = blockIdx.x << 7;
    {
        int bb = m0 >> 10, kl = klv[bb];
        if (kl > 1 && (m0 & 1023) >= kl) return;       // klen==1 needs ALL rows
    }
    const int lane = tid & 63, wave = tid >> 6;
    const int wm = 0;
    const int wn = wave * 32;
    const int rl = lane & 15, kg = lane >> 4;
    const int rl7 = lane & 7;

    int ca[NA]; const unsigned short* gA[NA];
    #pragma unroll
    for (int i = 0; i < NA; ++i) {
        int c = i * 256 + tid;
        int row = c >> 3, k8 = (c & 7) ^ (row & 7);
        ca[i] = c * 8;
        gA[i] = A + (size_t)(m0 + row) * 1024 + k8 * 8;
    }
    int cb[4]; const unsigned short* gB[4];
    #pragma unroll
    for (int i = 0; i < 4; ++i) {
        int c = i * 256 + tid;
        int row = c >> 3, k8 = (c & 7) ^ (row & 7);
        cb[i] = c * 8;
        gB[i] = B + (size_t)(n0 + row) * 1024 + k8 * 8;
    }

    int aoff[2][4], boff[2][FN];
    #pragma unroll
    for (int tt = 0; tt < 2; ++tt) {
        #pragma unroll
        for (int f = 0; f < 4; ++f)
            aoff[tt][f] = (wm + (f << 4) + rl) * 64 + (((tt * 4 + kg) ^ rl7) << 3);
        #pragma unroll
        for (int f = 0; f < FN; ++f)
            boff[tt][f] = (wn + (f << 4) + rl) * 64 + (((tt * 4 + kg) ^ rl7) << 3);
    }

    f32x4 acc[4][FN];
    #pragma unroll
    for (int i = 0; i < 4; ++i)
        #pragma unroll
        for (int j = 0; j < FN; ++j) {
            acc[i][j][0] = 0.f; acc[i][j][1] = 0.f;
            acc[i][j][2] = 0.f; acc[i][j][3] = 0.f;
        }

    const int NT = 16;
    #pragma unroll
    for (int i = 0; i < 4; ++i)  gl_lds16(gB[i], &Bs[0][cb[i]]);
    #pragma unroll
    for (int i = 0; i < NA; ++i) gl_lds16(gA[i], &As[0][ca[i]]);
    #pragma unroll
    for (int i = 0; i < 4; ++i)  gl_lds16(gB[i] + 64, &Bs[1][cb[i]]);
    #pragma unroll
    for (int i = 0; i < NA; ++i) gl_lds16(gA[i] + 64, &As[1][ca[i]]);

    for (int t = 0; t < NT; ++t) {
        const int cur = t & 1;
        if (t + 1 < NT) asm volatile("s_waitcnt vmcnt(6)" ::: "memory");
        else            asm volatile("s_waitcnt vmcnt(0)" ::: "memory");
        __builtin_amdgcn_s_barrier();
        __builtin_amdgcn_sched_barrier(0);
        f16x8 av[2][4], bv[2][FN];
        #pragma unroll
        for (int tt = 0; tt < 2; ++tt) {
            #pragma unroll
            for (int f = 0; f < 4; ++f)
                av[tt][f] = *(const f16x8*)&As[cur][aoff[tt][f]];
            #pragma unroll
            for (int f = 0; f < FN; ++f)
                bv[tt][f] = *(const f16x8*)&Bs[cur][boff[tt][f]];
        }
        asm volatile("s_waitcnt lgkmcnt(0)" ::: "memory");
        __builtin_amdgcn_sched_barrier(0);
        __builtin_amdgcn_s_barrier();
        __builtin_amdgcn_sched_barrier(0);
        if (t + 2 < NT) {
            const int ko = (t + 2) << 6;
            #pragma unroll
            for (int i = 0; i < 4; ++i)  gl_lds16(gB[i] + ko, &Bs[cur][cb[i]]);
            #pragma unroll
            for (int i = 0; i < NA; ++i) gl_lds16(gA[i] + ko, &As[cur][ca[i]]);
        }
        #pragma unroll
        for (int fm = 0; fm < 4; ++fm)
            #pragma unroll
            for (int fn = 0; fn < FN; ++fn) {
                acc[fm][fn] = __builtin_amdgcn_mfma_f32_16x16x32_f16(av[0][fm], bv[0][fn], acc[fm][fn], 0, 0, 0);
                acc[fm][fn] = __builtin_amdgcn_mfma_f32_16x16x32_f16(av[1][fm], bv[1][fn], acc[fm][fn], 0, 0, 0);
            }
    }

    #pragma unroll
    for (int fm = 0; fm < 4; ++fm) {
        int row = m0 + wm + (fm << 4) + (kg << 2);
        #pragma unroll
        for (int fn = 0; fn < FN; ++fn) {
            int col = n0 + wn + (fn << 4) + rl;
            ushort4 u;
            u.x = f2h(acc[fm][fn][0]); u.y = f2h(acc[fm][fn][1]);
            u.z = f2h(acc[fm][fn][2]); u.w = f2h(acc[fm][fn][3]);
            size_t a = ((size_t)((row >> 10) * 16 + (col >> 6)) * 64 + (col & 63)) * 1024 + (row & 1023);
            *(ushort4*)(Vt + a) = u;
        }
    }
}

// ---------------- MFMA flash attention (swapped QK, fp16, dbuf staging) ----------------
__global__ __launch_bounds__(256) void attn_mfma(
    const unsigned short* __restrict__ Qh,
    const unsigned short* __restrict__ Kh,
    const unsigned short* __restrict__ Vt,
    unsigned short* __restrict__ q16,
    const int* __restrict__ qlens, const int* __restrict__ klens)
{
    __shared__ __align__(16) unsigned short KS[2][4096];
    __shared__ __align__(16) unsigned short VtS[2][4096];
    __shared__ __align__(16) unsigned short Pl[4][1152];

    const int tid = threadIdx.x;
    const int bh = blockIdx.x & 63;
    const int qt = blockIdx.x >> 6;
    const int b = bh >> 4, h = bh & 15;
    const int qbase = qt * 64;
    const int qlen = qlens[b], klen = klens[b];
    if (qbase >= qlen) return;

    const int lane = tid & 63, wq = tid >> 6;
    const int rl = lane & 15, kg = lane >> 4, rl7 = lane & 7;
    const int gq = qbase + wq * 16 + rl;

    f16x8 qb[2];
    {
        const unsigned short* p1 = Qh + (size_t)(b * 1024 + gq) * 1024 + h * 64 + kg * 8;
        qb[0] = *(const f16x8*)p1;  qb[1] = *(const f16x8*)(p1 + 32);
    }

    const unsigned short* gK[2]; const unsigned short* gV[2];
    int cs[2];
    #pragma unroll
    for (int i = 0; i < 2; ++i) {
        int c = i * 256 + tid;
        int row = c >> 3, ch = (c & 7) ^ (row & 7);
        cs[i] = c * 8;
        gK[i] = Kh + (size_t)(b * 1024 + row) * 1024 + h * 64 + ch * 8;
        gV[i] = Vt + (size_t)(bh * 64 + row) * 1024 + ch * 8;
    }

    int akoff[4][2];
    #pragma unroll
    for (int mf = 0; mf < 4; ++mf)
        #pragma unroll
        for (int kh = 0; kh < 2; ++kh)
            akoff[mf][kh] = (mf * 16 + rl) * 64 + (((kg + 4 * kh) ^ rl7) << 3);

    f32x4 o[4];
    #pragma unroll
    for (int i = 0; i < 4; ++i) { o[i][0]=0.f; o[i][1]=0.f; o[i][2]=0.f; o[i][3]=0.f; }
    float m_run = -3.0e38f, l_run = 0.f;
    const int nt = (klen == 1) ? (T_ / 64) : ((klen + 63) >> 6);

    gl_lds16(gK[0], &KS[0][cs[0]]);
    gl_lds16(gK[1], &KS[0][cs[1]]);
    gl_lds16(gV[0], &VtS[0][cs[0]]);
    gl_lds16(gV[1], &VtS[0][cs[1]]);
    gl_lds16(gK[0] + 65536, &KS[1][cs[0]]);
    gl_lds16(gK[1] + 65536, &KS[1][cs[1]]);
    gl_lds16(gV[0] + 64,    &VtS[1][cs[0]]);
    gl_lds16(gV[1] + 64,    &VtS[1][cs[1]]);

    for (int kb = 0; kb < nt; ++kb) {
        const int cur = kb & 1;
        const int kbase = kb * 64;
        if (kb + 1 < nt) asm volatile("s_waitcnt vmcnt(4)" ::: "memory");
        else             asm volatile("s_waitcnt vmcnt(0)" ::: "memory");
        __builtin_amdgcn_s_barrier();
        __builtin_amdgcn_sched_barrier(0);

        float v[4][4];
        __builtin_amdgcn_s_setprio(1);
        #pragma unroll
        for (int mf = 0; mf < 4; ++mf) {
            f32x4 s; s[0]=0.f; s[1]=0.f; s[2]=0.f; s[3]=0.f;
            f16x8 a0 = *(const f16x8*)&KS[cur][akoff[mf][0]];
            f16x8 a1 = *(const f16x8*)&KS[cur][akoff[mf][1]];
            s = __builtin_amdgcn_mfma_f32_16x16x32_f16(a0, qb[0], s, 0, 0, 0);
            s = __builtin_amdgcn_mfma_f32_16x16x32_f16(a1, qb[1], s, 0, 0, 0);
            #pragma unroll
            for (int r = 0; r < 4; ++r) {
                int gk = kbase + mf * 16 + kg * 4 + r;
                float x = s[r] * 0.125f;
                if (gk >= klen || gk == gq) x = NEG_;
                v[mf][r] = x;
            }
        }
        __builtin_amdgcn_s_setprio(0);
        float mt = -3.0e38f;
        #pragma unroll
        for (int mf = 0; mf < 4; ++mf)
            #pragma unroll
            for (int r = 0; r < 4; ++r) mt = fmaxf(mt, v[mf][r]);
        mt = fmaxf(mt, __shfl_xor(mt, 16));
        mt = fmaxf(mt, __shfl_xor(mt, 32));
        float mnew = fmaxf(m_run, mt);
        float fac = __expf(m_run - mnew);
        float sum = 0.f;
        #pragma unroll
        for (int mf = 0; mf < 4; ++mf) {
            ushort4 pb;
            pb.x = f2h(__expf(v[mf][0] - mnew));
            pb.y = f2h(__expf(v[mf][1] - mnew));
            pb.z = f2h(__expf(v[mf][2] - mnew));
            pb.w = f2h(__expf(v[mf][3] - mnew));
            sum += h2f(pb.x) + h2f(pb.y) + h2f(pb.z) + h2f(pb.w);
            *(ushort4*)&Pl[wq][rl * 72 + mf * 16 + kg * 4] = pb;
        }
        sum += __shfl_xor(sum, 16);
        sum += __shfl_xor(sum, 32);
        l_run = l_run * fac + sum;
        m_run = mnew;
        #pragma unroll
        for (int i = 0; i < 4; ++i) {
            o[i][0] *= fac; o[i][1] *= fac; o[i][2] *= fac; o[i][3] *= fac;
        }
        f16x8 bp0 = *(const f16x8*)&Pl[wq][rl * 72 + kg * 8];
        f16x8 bp1 = *(const f16x8*)&Pl[wq][rl * 72 + 32 + kg * 8];
        __builtin_amdgcn_s_setprio(1);
        #pragma unroll
        for (int dmf = 0; dmf < 4; ++dmf) {
            f16x8 a0 = *(const f16x8*)&VtS[cur][akoff[dmf][0]];
            f16x8 a1 = *(const f16x8*)&VtS[cur][akoff[dmf][1]];
            o[dmf] = __builtin_amdgcn_mfma_f32_16x16x32_f16(a0, bp0, o[dmf], 0, 0, 0);
            o[dmf] = __builtin_amdgcn_mfma_f32_16x16x32_f16(a1, bp1, o[dmf], 0, 0, 0);
        }
        __builtin_amdgcn_s_setprio(0);
        __builtin_amdgcn_s_barrier();
        __builtin_amdgcn_sched_barrier(0);
        if (kb + 2 < nt) {
            const size_t ko = (size_t)(kbase + 128) * 1024;
            gl_lds16(gK[0] + ko, &KS[cur][cs[0]]);
            gl_lds16(gK[1] + ko, &KS[cur][cs[1]]);
            gl_lds16(gV[0] + kbase + 128, &VtS[cur][cs[0]]);
            gl_lds16(gV[1] + kbase + 128, &VtS[cur][cs[1]]);
        }
    }

    float invl = (gq < qlen) ? (1.f / l_run) : 0.f;
    #pragma unroll
    for (int dmf = 0; dmf < 4; ++dmf)
        #pragma unroll
        for (int r = 0; r < 4; ++r) {
            int dh = dmf * 16 + kg * 4 + r;
            size_t a = (size_t)(b * 1024 + gq) * 1024 + h * 64 + dh;
            q16[a] = f2h(o[dmf][r] * invl + h2f(q16[a]));
        }
}

// ======== FFN1: 256x256 8-wave interleaved-phase GEMM + relu-colsum ========
__global__ __launch_bounds__(512, 2) void ffn1_8p(
    const unsigned short* __restrict__ A,
    const unsigned short* __restrict__ B,
    float* __restrict__ hpart)
{
    __shared__ __align__(16) unsigned short As[2][16384];
    __shared__ __align__(16) unsigned short Bs[2][16384];
    __shared__ float hp[8][64];
    const int tid = threadIdx.x;
    const int m0 = blockIdx.y << 8, n0 = blockIdx.x << 8;
    const int lane = tid & 63, wave = tid >> 6;
    const int wm = wave >> 2, wn = wave & 3;
    const int rl = lane & 15, kg = lane >> 4, rl7 = lane & 7;

    const int row0 = tid >> 3;
    const int k8c = (tid & 7) ^ (row0 & 7);
    const int cs0 = tid * 8;
    const int gofs = row0 * 1024 + k8c * 8;
    const unsigned short* Ap = A + (size_t)m0 * 1024 + gofs;
    const unsigned short* Bp = B + (size_t)n0 * 1024 + gofs;

    const int base_a = ((wm * 128 + rl) * 8 + (kg ^ rl7)) * 8;
    const int base_b = (((wn >> 1) * 128 + (wn & 1) * 64 + rl) * 8 + (kg ^ rl7)) * 8;

    f32x4 acc[8][4];
    #pragma unroll
    for (int i = 0; i < 8; ++i)
        #pragma unroll
        for (int j = 0; j < 4; ++j) {
            acc[i][j][0] = 0.f; acc[i][j][1] = 0.f;
            acc[i][j][2] = 0.f; acc[i][j][3] = 0.f;
        }

    const int NT = 16;
    #pragma unroll
    for (int i = 0; i < 4; ++i) gl_lds16(Ap + i * 65536, &As[0][cs0 + i * 4096]);
    #pragma unroll
    for (int i = 0; i < 4; ++i) gl_lds16(Bp + i * 65536, &Bs[0][cs0 + i * 4096]);
    #pragma unroll
    for (int i = 0; i < 4; ++i) gl_lds16(Ap + i * 65536 + 64, &As[1][cs0 + i * 4096]);
    #pragma unroll
    for (int i = 0; i < 4; ++i) gl_lds16(Bp + i * 65536 + 64, &Bs[1][cs0 + i * 4096]);

    for (int t = 0; t < NT; ++t) {
        const int cur = t & 1;
        if (t + 1 < NT) asm volatile("s_waitcnt vmcnt(8)" ::: "memory");
        else            asm volatile("s_waitcnt vmcnt(0)" ::: "memory");
        __builtin_amdgcn_s_barrier();
        __builtin_amdgcn_sched_barrier(0);
        f16x8 av[8][2], bv[4][2];
        #pragma unroll
        for (int f = 0; f < 8; ++f) {
            int o = base_a + f * 1024;
            av[f][0] = *(const f16x8*)&As[cur][o];
            av[f][1] = *(const f16x8*)&As[cur][o ^ 32];
        }
        #pragma unroll
        for (int fn = 0; fn < 4; ++fn) {
            int o = base_b + fn * 1024;
            bv[fn][0] = *(const f16x8*)&Bs[cur][o];
            bv[fn][1] = *(const f16x8*)&Bs[cur][o ^ 32];
        }
        asm volatile("s_waitcnt lgkmcnt(0)" ::: "memory");
        __builtin_amdgcn_sched_barrier(0);
        __builtin_amdgcn_s_barrier();
        __builtin_amdgcn_sched_barrier(0);
        const bool pre = (t + 2 < NT);
        const int ko = (t + 2) << 6;
        #pragma unroll
        for (int p = 0; p < 4; ++p) {
            if (pre) {
                if (p < 2) {
                    gl_lds16(Ap + (2*p) * 65536 + ko,     &As[cur][cs0 + (2*p) * 4096]);
                    gl_lds16(Ap + (2*p + 1) * 65536 + ko, &As[cur][cs0 + (2*p + 1) * 4096]);
                } else {
                    gl_lds16(Bp + (2*p - 4) * 65536 + ko, &Bs[cur][cs0 + (2*p - 4) * 4096]);
                    gl_lds16(Bp + (2*p - 3) * 65536 + ko, &Bs[cur][cs0 + (2*p - 3) * 4096]);
                }
            }
            __builtin_amdgcn_sched_barrier(0);
            __builtin_amdgcn_s_setprio(1);
            #pragma unroll
            for (int f = 2 * p; f < 2 * p + 2; ++f)
                #pragma unroll
                for (int fn = 0; fn < 4; ++fn) {
                    acc[f][fn] = __builtin_amdgcn_mfma_f32_16x16x32_f16(av[f][0], bv[fn][0], acc[f][fn], 0, 0, 0);
                    acc[f][fn] = __builtin_amdgcn_mfma_f32_16x16x32_f16(av[f][1], bv[fn][1], acc[f][fn], 0, 0, 0);
                }
            __builtin_amdgcn_s_setprio(0);
            __builtin_amdgcn_sched_barrier(0);
        }
    }

    #pragma unroll
    for (int fn = 0; fn < 4; ++fn) {
        float p = 0.f;
        #pragma unroll
        for (int f = 0; f < 8; ++f)
            #pragma unroll
            for (int r = 0; r < 4; ++r) p += fmaxf(acc[f][fn][r], 0.f);
        p += __shfl_xor(p, 16);
        p += __shfl_xor(p, 32);
        if (kg == 0) hp[wave][fn * 16 + rl] = p;
    }
    __syncthreads();
    if (tid < 256) {
        int wn2 = tid >> 6, cc = tid & 63;
        float s = hp[wn2][cc] + hp[wn2 + 4][cc];
        hpart[(size_t)blockIdx.y * 4096 + n0 + wn2 * 64 + cc] = s;
    }
}

// ======== tail: mean16 (y==32) + final_partial (y<32), one dispatch ========
__global__ __launch_bounds__(256) void tail(const unsigned short* __restrict__ q16,
                                            const float* __restrict__ Hpart,
                                            const float* __restrict__ fw2,
                                            float* __restrict__ Pout,
                                            float* __restrict__ Mres)
{
    int tid = threadIdx.x;
    if (blockIdx.y == 32) {
        // mean over T of q16: block x covers batch (x>>2), col-chunk (x&3)*256
        __shared__ float red[4][256];
        int b = blockIdx.x >> 2;
        int dbase = (blockIdx.x & 3) * 256;
        int tq = tid >> 6, dd = tid & 63;
        int d = dbase + dd * 4;
        const unsigned short* p = q16 + ((size_t)b * T_ + tq * 256) * 1024 + d;
        float s0 = 0.f, s1 = 0.f, s2 = 0.f, s3 = 0.f;
        for (int t = 0; t < 256; ++t) {
            ushort4 v = *(const ushort4*)(p + (size_t)t * 1024);
            s0 += h2f(v.x); s1 += h2f(v.y); s2 += h2f(v.z); s3 += h2f(v.w);
        }
        red[tq][dd*4] = s0; red[tq][dd*4+1] = s1; red[tq][dd*4+2] = s2; red[tq][dd*4+3] = s3;
        __syncthreads();
        if (tq == 0) {
            #pragma unroll
            for (int j = 0; j < 4; ++j) {
                float a = red[0][dd*4+j] + red[1][dd*4+j] + red[2][dd*4+j] + red[3][dd*4+j];
                Mres[(size_t)b * 1024 + d + j] = a * (1.f/1024.f);
            }
        }
        return;
    }
    __shared__ float red[4][4][64];
    __shared__ float hm[4][128];
    #pragma unroll
    for (int s = 0; s < 2; ++s) {
        int idx = s * 256 + tid;
        int bb = idx >> 7, jl = idx & 127;
        int j = blockIdx.y * 128 + jl;
        float acc = 0.f;
        #pragma unroll
        for (int i = 0; i < 4; ++i)
            acc += Hpart[((size_t)(bb * 4 + i)) * 4096 + j];
        hm[bb][jl] = acc * (1.f / 1024.f);
    }
    __syncthreads();
    int dd = tid & 63;
    int d = blockIdx.x * 64 + dd;
    int jq = tid >> 6;
    float s4[4] = {0.f, 0.f, 0.f, 0.f};
    for (int jj = 0; jj < 32; ++jj) {
        int jl = jq * 32 + jj;
        int j = blockIdx.y * 128 + jl;
        float wv = fw2[(size_t)j * 1024 + d];
        s4[0] += hm[0][jl] * wv;
        s4[1] += hm[1][jl] * wv;
        s4[2] += hm[2][jl] * wv;
        s4[3] += hm[3][jl] * wv;
    }
    #pragma unroll
    for (int bb = 0; bb < 4; ++bb) red[jq][bb][dd] = s4[bb];
    __syncthreads();
    if (jq == 0) {
        #pragma unroll
        for (int bb = 0; bb < 4; ++bb) {
            float tot = red[0][bb][dd] + red[1][bb][dd] + red[2][bb][dd] + red[3][bb][dd];
            Pout[((size_t)blockIdx.y * 4 + bb) * 1024 + d] = tot;
        }
    }
}

// ---------------- out[b][d] = Mres[b][d] + sum_{jy<32} Pout[jy][b][d] ----------------
__global__ __launch_bounds__(256) void reduce_out(const float* __restrict__ Mres,
                                                  const float* __restrict__ Pout,
                                                  float* __restrict__ out)
{
    int idx = blockIdx.x * 256 + threadIdx.x;
    int b = idx >> 10, d = idx & 1023;
    float s = Mres[(size_t)b * 1024 + d];
    #pragma unroll
    for (int jy = 0; jy < 32; ++jy)
        s += Pout[((size_t)jy * 4 + b) * 1024 + d];
    out[(size_t)b * 1024 + d] = s;
}

extern "C" void kernel_launch(void* const* d_in, const int* in_sizes, int n_in,
                              void* d_out, int out_size, void* d_ws, size_t ws_size,
                              hipStream_t stream)
{
    const float* queries = (const float*)d_in[0];
    const int*   qlens   = (const int*)d_in[2];
    const int*   klens   = (const int*)d_in[3];
    const float* pe_q    = (const float*)d_in[4];
    const float* pe_k    = (const float*)d_in[5];
    const float* Wq      = (const float*)d_in[6];
    const float* Wk      = (const float*)d_in[7];
    const float* Wv      = (const float*)d_in[8];
    const float* fw1     = (const float*)d_in[9];
    const float* fw2     = (const float*)d_in[10];
    float* out = (float*)d_out;

    char* w = (char*)d_ws;
    unsigned short* Qh   = (unsigned short*)(w);                  // [0,8)
    unsigned short* A2   = (unsigned short*)(w + (8ll  << 20));   // [8,24)
    unsigned short* q16  = A2;                                    // [8,16)
    unsigned short* Kh16 = (unsigned short*)(w + (24ll << 20));   // [24,32)
    unsigned short* B2   = (unsigned short*)(w + (32ll << 20));   // [32,36)
    unsigned short* WvT  = (unsigned short*)(w + (36ll << 20));   // [36,38)
    unsigned short* Vt   = (unsigned short*)(w + (38ll << 20));   // [38,46)
    unsigned short* fw1T = (unsigned short*)(w + (46ll << 20));   // [46,54)
    float*          Hpart= (float*)(w + (54ll << 20));            // 256 KB
    float*          Mres = (float*)(w + (55ll << 20));            // 16 KB
    float*          Pout = (float*)(w + (56ll << 20));            // 512 KB

    // 1) all conversions, one launch
    conv_all<<<15360, 256, 0, stream>>>(queries, pe_q, pe_k, Wq, Wk, Wv, fw1, klens,
                                        A2, B2, WvT, fw1T);
    // 2) stacked [Q|K] GEMM, 256x256 8-phase, len-skip
    qk_8p<<<dim3(8, 32), 512, 0, stream>>>(A2, B2, Qh, Kh16, qlens, klens);
    // 3) V = Kh16 @ Wv, fp16 transposed Vt[b,h][dh][t]
    gemm_v<<<dim3(8, 64), 256, 0, stream>>>(Kh16, WvT, Vt, klens);
    // 4) MFMA attention + residual -> q16 in place
    attn_mfma<<<1024, 256, 0, stream>>>(Qh, Kh16, Vt, q16, qlens, klens);
    // 5) FFN1: 256x256 8-wave interleaved schedule, fused relu-colsum
    ffn1_8p<<<dim3(16, 16), 512, 0, stream>>>(q16, fw1T, Hpart);
    // 6) tail: mean_t(res) + FFN2 partials, one dispatch
    tail<<<dim3(16, 33), 256, 0, stream>>>(q16, Hpart, fw2, Pout, Mres);
    reduce_out<<<16, 256, 0, stream>>>(Mres, Pout, out);
}

// Round 17
// 118.074 us; speedup vs baseline: 1.0844x; 1.0844x over previous
//
#include <hip/hip_runtime.h>

#define T_ 1024
#define D_ 1024
#define B_ 4
#define H_ 16
#define DH_ 64
#define M_ (B_*T_)                 // 4096
#define NEG_ (-4294967295.0f)

typedef __attribute__((ext_vector_type(8))) _Float16 f16x8;
typedef __attribute__((ext_vector_type(4))) float f32x4;

__device__ __forceinline__ unsigned short f2h(float f) {
    _Float16 h = (_Float16)f; unsigned short u; __builtin_memcpy(&u, &h, 2); return u;
}
__device__ __forceinline__ float h2f(unsigned short u) {
    _Float16 h; __builtin_memcpy(&h, &u, 2); return (float)h;
}

typedef const unsigned int __attribute__((address_space(1)))* gas_p;
typedef unsigned int __attribute__((address_space(3)))* las_p;
__device__ __forceinline__ void gl_lds16(const void* g, void* l) {
    __builtin_amdgcn_global_load_lds((gas_p)g, (las_p)l, 16, 0, 0);
}

// ================= fused conversions (one launch) =================
__global__ __launch_bounds__(256) void conv_all(const float* __restrict__ q,
                                                const float* __restrict__ peq,
                                                const float* __restrict__ pek,
                                                const float* __restrict__ Wq,
                                                const float* __restrict__ Wk,
                                                const float* __restrict__ Wv,
                                                const float* __restrict__ fw1,
                                                const int* __restrict__ klv,
                                                unsigned short* __restrict__ A2,
                                                unsigned short* __restrict__ B2,
                                                unsigned short* __restrict__ WvT,
                                                unsigned short* __restrict__ fw1T)
{
    int blk = blockIdx.x;
    if (blk < 8192) {
        int i = blk * 256 + threadIdx.x;
        int m = i >> 8, c4 = (i & 255) << 2;
        int mq = m & 4095;
        if (m >= 4096) {
            int row = m - 4096;
            int kl = klv[row >> 10];
            if (kl > 1 && (row & 1023) >= kl) return;   // dead k_in row
        }
        float4 qv = *(const float4*)(q + (size_t)mq * D_ + c4);
        float4 p  = *(const float4*)(peq + (size_t)(m & (T_-1)) * D_ + c4);
        ushort4 h;
        if (m < 4096) {
            h.x = f2h(qv.x + 32.f*p.x); h.y = f2h(qv.y + 32.f*p.y);
            h.z = f2h(qv.z + 32.f*p.z); h.w = f2h(qv.w + 32.f*p.w);
        } else {
            float4 pk = *(const float4*)(pek + (size_t)(m & (T_-1)) * D_ + c4);
            h.x = f2h(qv.x + 32.f*(p.x + pk.x)); h.y = f2h(qv.y + 32.f*(p.y + pk.y));
            h.z = f2h(qv.z + 32.f*(p.z + pk.z)); h.w = f2h(qv.w + 32.f*(p.w + pk.w));
        }
        *(ushort4*)(A2 + (size_t)m * 1024 + c4) = h;
        return;
    }
    __shared__ float t[32][33];
    int r = threadIdx.x >> 5, c = threadIdx.x & 31;
    if (blk < 10240) {              // conv_w2
        int l = blk - 8192;
        int z = l >> 10, k0 = ((l >> 5) & 31) * 32, n0 = (l & 31) * 32;
        const float* W = z ? Wk : Wq;
        #pragma unroll
        for (int rr = 0; rr < 4; ++rr)
            t[r + 8*rr][c] = W[(size_t)(k0 + r + 8*rr) * 1024 + n0 + c];
        __syncthreads();
        #pragma unroll
        for (int rr = 0; rr < 4; ++rr)
            B2[(size_t)(z * 1024 + n0 + r + 8*rr) * 1024 + k0 + c] = f2h(t[c][r + 8*rr]);
    } else if (blk < 11264) {       // conv_wT(Wv)
        int l = blk - 10240;
        int k0 = (l >> 5) * 32, n0 = (l & 31) * 32;
        #pragma unroll
        for (int rr = 0; rr < 4; ++rr)
            t[r + 8*rr][c] = Wv[(size_t)(k0 + r + 8*rr) * 1024 + n0 + c];
        __syncthreads();
        #pragma unroll
        for (int rr = 0; rr < 4; ++rr)
            WvT[(size_t)(n0 + r + 8*rr) * 1024 + k0 + c] = f2h(t[c][r + 8*rr]);
    } else {                        // conv_wT(fw1)
        int l = blk - 11264;
        int k0 = (l >> 7) * 32, n0 = (l & 127) * 32;
        #pragma unroll
        for (int rr = 0; rr < 4; ++rr)
            t[r + 8*rr][c] = fw1[(size_t)(k0 + r + 8*rr) * 4096 + n0 + c];
        __syncthreads();
        #pragma unroll
        for (int rr = 0; rr < 4; ++rr)
            fw1T[(size_t)(n0 + r + 8*rr) * 1024 + k0 + c] = f2h(t[c][r + 8*rr]);
    }
}

// ======== QK: 128x128 counted-vmcnt 2-phase GEMM (proven), stacked epilogue ========
__global__ __launch_bounds__(256) void qk_2p(
    const unsigned short* __restrict__ A,     // A2 [8192][1024]
    const unsigned short* __restrict__ B,     // B2 [2048][1024]
    unsigned short* __restrict__ Qh, unsigned short* __restrict__ Kh16,
    const int* __restrict__ qlv, const int* __restrict__ klv)
{
    constexpr int BM = 128, WN = 2, FN = 4, NA = 4;
    __shared__ __align__(16) unsigned short As[2][BM * 64];
    __shared__ __align__(16) unsigned short Bs[2][128 * 64];
    const int tid = threadIdx.x;
    const int m0 = blockIdx.y * BM, n0 = blockIdx.x << 7;
    if (m0 < 4096) {                               // q_in rows -> Q cols only
        if (n0 >= 1024) return;
        if ((m0 & 1023) >= qlv[m0 >> 10]) return;
    } else {                                       // k_in rows -> K cols only
        if (n0 < 1024) return;
        int kl = klv[(m0 - 4096) >> 10];
        if (kl > 1 && (m0 & 1023) >= kl) return;
    }
    const int lane = tid & 63, wave = tid >> 6;
    const int wm = (wave / WN) * 64;
    const int wn = (wave % WN) * 64;
    const int rl = lane & 15, kg = lane >> 4;
    const int rl7 = lane & 7;

    int ca[NA]; const unsigned short* gA[NA];
    #pragma unroll
    for (int i = 0; i < NA; ++i) {
        int c = i * 256 + tid;
        int row = c >> 3, k8 = (c & 7) ^ (row & 7);
        ca[i] = c * 8;
        gA[i] = A + (size_t)(m0 + row) * 1024 + k8 * 8;
    }
    int cb[4]; const unsigned short* gB[4];
    #pragma unroll
    for (int i = 0; i < 4; ++i) {
        int c = i * 256 + tid;
        int row = c >> 3, k8 = (c & 7) ^ (row & 7);
        cb[i] = c * 8;
        gB[i] = B + (size_t)(n0 + row) * 1024 + k8 * 8;
    }

    int aoff[2][4], boff[2][FN];
    #pragma unroll
    for (int tt = 0; tt < 2; ++tt) {
        #pragma unroll
        for (int f = 0; f < 4; ++f)
            aoff[tt][f] = (wm + (f << 4) + rl) * 64 + (((tt * 4 + kg) ^ rl7) << 3);
        #pragma unroll
        for (int f = 0; f < FN; ++f)
            boff[tt][f] = (wn + (f << 4) + rl) * 64 + (((tt * 4 + kg) ^ rl7) << 3);
    }

    f32x4 acc[4][FN];
    #pragma unroll
    for (int i = 0; i < 4; ++i)
        #pragma unroll
        for (int j = 0; j < FN; ++j) {
            acc[i][j][0] = 0.f; acc[i][j][1] = 0.f;
            acc[i][j][2] = 0.f; acc[i][j][3] = 0.f;
        }

    const int NT = 16;
    #pragma unroll
    for (int i = 0; i < 4; ++i)  gl_lds16(gB[i], &Bs[0][cb[i]]);
    #pragma unroll
    for (int i = 0; i < NA; ++i) gl_lds16(gA[i], &As[0][ca[i]]);
    #pragma unroll
    for (int i = 0; i < 4; ++i)  gl_lds16(gB[i] + 64, &Bs[1][cb[i]]);
    #pragma unroll
    for (int i = 0; i < NA; ++i) gl_lds16(gA[i] + 64, &As[1][ca[i]]);

    for (int t = 0; t < NT; ++t) {
        const int cur = t & 1;
        if (t + 1 < NT) asm volatile("s_waitcnt vmcnt(8)" ::: "memory");
        else            asm volatile("s_waitcnt vmcnt(0)" ::: "memory");
        __builtin_amdgcn_s_barrier();
        __builtin_amdgcn_sched_barrier(0);
        f16x8 av[2][4], bv[2][FN];
        #pragma unroll
        for (int tt = 0; tt < 2; ++tt) {
            #pragma unroll
            for (int f = 0; f < 4; ++f)
                av[tt][f] = *(const f16x8*)&As[cur][aoff[tt][f]];
            #pragma unroll
            for (int f = 0; f < FN; ++f)
                bv[tt][f] = *(const f16x8*)&Bs[cur][boff[tt][f]];
        }
        asm volatile("s_waitcnt lgkmcnt(0)" ::: "memory");
        __builtin_amdgcn_sched_barrier(0);
        __builtin_amdgcn_s_barrier();
        __builtin_amdgcn_sched_barrier(0);
        if (t + 2 < NT) {
            const int ko = (t + 2) << 6;
            #pragma unroll
            for (int i = 0; i < 4; ++i)  gl_lds16(gB[i] + ko, &Bs[cur][cb[i]]);
            #pragma unroll
            for (int i = 0; i < NA; ++i) gl_lds16(gA[i] + ko, &As[cur][ca[i]]);
        }
        #pragma unroll
        for (int fm = 0; fm < 4; ++fm)
            #pragma unroll
            for (int fn = 0; fn < FN; ++fn) {
                acc[fm][fn] = __builtin_amdgcn_mfma_f32_16x16x32_f16(av[0][fm], bv[0][fn], acc[fm][fn], 0, 0, 0);
                acc[fm][fn] = __builtin_amdgcn_mfma_f32_16x16x32_f16(av[1][fm], bv[1][fn], acc[fm][fn], 0, 0, 0);
            }
    }

    const bool isQ = (m0 < 4096);
    #pragma unroll
    for (int fm = 0; fm < 4; ++fm) {
        int row = m0 + wm + (fm << 4) + (kg << 2);
        #pragma unroll
        for (int fn = 0; fn < FN; ++fn) {
            int col = n0 + wn + (fn << 4) + rl;
            #pragma unroll
            for (int r = 0; r < 4; ++r) {
                unsigned short val = f2h(acc[fm][fn][r]);
                if (isQ) Qh[(size_t)(row + r) * 1024 + col] = val;
                else     Kh16[(size_t)(row + r - 4096) * 1024 + (col - 1024)] = val;
            }
        }
    }
}

// ======== V GEMM: counted-vmcnt pipelined fp16 MFMA, BM=64/BK=64 (proven) ========
__global__ __launch_bounds__(256) void gemm_v(
    const unsigned short* __restrict__ A,     // Kh16 [4096][1024]
    const unsigned short* __restrict__ B,     // WvT [1024][1024]
    unsigned short* __restrict__ Vt,          // [64 bh][64 dh][1024 t]
    const int* __restrict__ klv)
{
    constexpr int BM = 64, FN = 2, NA = 2;
    __shared__ __align__(16) unsigned short As[2][BM * 64];
    __shared__ __align__(16) unsigned short Bs[2][128 * 64];
    const int tid = threadIdx.x;
    const int m0 = blockIdx.y * BM, n0 = blockIdx.x << 7;
    {
        int bb = m0 >> 10, kl = klv[bb];
        if (kl > 1 && (m0 & 1023) >= kl) return;       // klen==1 needs ALL rows
    }
    const int lane = tid & 63, wave = tid >> 6;
    const int wn = wave * 32;
    const int rl = lane & 15, kg = lane >> 4;
    const int rl7 = lane & 7;

    int ca[NA]; const unsigned short* gA[NA];
    #pragma unroll
    for (int i = 0; i < NA; ++i) {
        int c = i * 256 + tid;
        int row = c >> 3, k8 = (c & 7) ^ (row & 7);
        ca[i] = c * 8;
        gA[i] = A + (size_t)(m0 + row) * 1024 + k8 * 8;
    }
    int cb[4]; const unsigned short* gB[4];
    #pragma unroll
    for (int i = 0; i < 4; ++i) {
        int c = i * 256 + tid;
        int row = c >> 3, k8 = (c & 7) ^ (row & 7);
        cb[i] = c * 8;
        gB[i] = B + (size_t)(n0 + row) * 1024 + k8 * 8;
    }

    int aoff[2][4], boff[2][FN];
    #pragma unroll
    for (int tt = 0; tt < 2; ++tt) {
        #pragma unroll
        for (int f = 0; f < 4; ++f)
            aoff[tt][f] = ((f << 4) + rl) * 64 + (((tt * 4 + kg) ^ rl7) << 3);
        #pragma unroll
        for (int f = 0; f < FN; ++f)
            boff[tt][f] = (wn + (f << 4) + rl) * 64 + (((tt * 4 + kg) ^ rl7) << 3);
    }

    f32x4 acc[4][FN];
    #pragma unroll
    for (int i = 0; i < 4; ++i)
        #pragma unroll
        for (int j = 0; j < FN; ++j) {
            acc[i][j][0] = 0.f; acc[i][j][1] = 0.f;
            acc[i][j][2] = 0.f; acc[i][j][3] = 0.f;
        }

    const int NT = 16;
    #pragma unroll
    for (int i = 0; i < 4; ++i)  gl_lds16(gB[i], &Bs[0][cb[i]]);
    #pragma unroll
    for (int i = 0; i < NA; ++i) gl_lds16(gA[i], &As[0][ca[i]]);
    #pragma unroll
    for (int i = 0; i < 4; ++i)  gl_lds16(gB[i] + 64, &Bs[1][cb[i]]);
    #pragma unroll
    for (int i = 0; i < NA; ++i) gl_lds16(gA[i] + 64, &As[1][ca[i]]);

    for (int t = 0; t < NT; ++t) {
        const int cur = t & 1;
        if (t + 1 < NT) asm volatile("s_waitcnt vmcnt(6)" ::: "memory");
        else            asm volatile("s_waitcnt vmcnt(0)" ::: "memory");
        __builtin_amdgcn_s_barrier();
        __builtin_amdgcn_sched_barrier(0);
        f16x8 av[2][4], bv[2][FN];
        #pragma unroll
        for (int tt = 0; tt < 2; ++tt) {
            #pragma unroll
            for (int f = 0; f < 4; ++f)
                av[tt][f] = *(const f16x8*)&As[cur][aoff[tt][f]];
            #pragma unroll
            for (int f = 0; f < FN; ++f)
                bv[tt][f] = *(const f16x8*)&Bs[cur][boff[tt][f]];
        }
        asm volatile("s_waitcnt lgkmcnt(0)" ::: "memory");
        __builtin_amdgcn_sched_barrier(0);
        __builtin_amdgcn_s_barrier();
        __builtin_amdgcn_sched_barrier(0);
        if (t + 2 < NT) {
            const int ko = (t + 2) << 6;
            #pragma unroll
            for (int i = 0; i < 4; ++i)  gl_lds16(gB[i] + ko, &Bs[cur][cb[i]]);
            #pragma unroll
            for (int i = 0; i < NA; ++i) gl_lds16(gA[i] + ko, &As[cur][ca[i]]);
        }
        #pragma unroll
        for (int fm = 0; fm < 4; ++fm)
            #pragma unroll
            for (int fn = 0; fn < FN; ++fn) {
                acc[fm][fn] = __builtin_amdgcn_mfma_f32_16x16x32_f16(av[0][fm], bv[0][fn], acc[fm][fn], 0, 0, 0);
                acc[fm][fn] = __builtin_amdgcn_mfma_f32_16x16x32_f16(av[1][fm], bv[1][fn], acc[fm][fn], 0, 0, 0);
            }
    }

    #pragma unroll
    for (int fm = 0; fm < 4; ++fm) {
        int row = m0 + (fm << 4) + (kg << 2);
        #pragma unroll
        for (int fn = 0; fn < FN; ++fn) {
            int col = n0 + wn + (fn << 4) + rl;
            ushort4 u;
            u.x = f2h(acc[fm][fn][0]); u.y = f2h(acc[fm][fn][1]);
            u.z = f2h(acc[fm][fn][2]); u.w = f2h(acc[fm][fn][3]);
            size_t a = ((size_t)((row >> 10) * 16 + (col >> 6)) * 64 + (col & 63)) * 1024 + (row & 1023);
            *(ushort4*)(Vt + a) = u;
        }
    }
}

// ---------------- MFMA flash attention (swapped QK, fp16, dbuf staging) ----------------
__global__ __launch_bounds__(256) void attn_mfma(
    const unsigned short* __restrict__ Qh,
    const unsigned short* __restrict__ Kh,
    const unsigned short* __restrict__ Vt,
    unsigned short* __restrict__ q16,
    const int* __restrict__ qlens, const int* __restrict__ klens)
{
    __shared__ __align__(16) unsigned short KS[2][4096];
    __shared__ __align__(16) unsigned short VtS[2][4096];
    __shared__ __align__(16) unsigned short Pl[4][1152];

    const int tid = threadIdx.x;
    const int bh = blockIdx.x & 63;
    const int qt = blockIdx.x >> 6;
    const int b = bh >> 4, h = bh & 15;
    const int qbase = qt * 64;
    const int qlen = qlens[b], klen = klens[b];
    if (qbase >= qlen) return;

    const int lane = tid & 63, wq = tid >> 6;
    const int rl = lane & 15, kg = lane >> 4, rl7 = lane & 7;
    const int gq = qbase + wq * 16 + rl;

    f16x8 qb[2];
    {
        const unsigned short* p1 = Qh + (size_t)(b * 1024 + gq) * 1024 + h * 64 + kg * 8;
        qb[0] = *(const f16x8*)p1;  qb[1] = *(const f16x8*)(p1 + 32);
    }

    const unsigned short* gK[2]; const unsigned short* gV[2];
    int cs[2];
    #pragma unroll
    for (int i = 0; i < 2; ++i) {
        int c = i * 256 + tid;
        int row = c >> 3, ch = (c & 7) ^ (row & 7);
        cs[i] = c * 8;
        gK[i] = Kh + (size_t)(b * 1024 + row) * 1024 + h * 64 + ch * 8;
        gV[i] = Vt + (size_t)(bh * 64 + row) * 1024 + ch * 8;
    }

    int akoff[4][2];
    #pragma unroll
    for (int mf = 0; mf < 4; ++mf)
        #pragma unroll
        for (int kh = 0; kh < 2; ++kh)
            akoff[mf][kh] = (mf * 16 + rl) * 64 + (((kg + 4 * kh) ^ rl7) << 3);

    f32x4 o[4];
    #pragma unroll
    for (int i = 0; i < 4; ++i) { o[i][0]=0.f; o[i][1]=0.f; o[i][2]=0.f; o[i][3]=0.f; }
    float m_run = -3.0e38f, l_run = 0.f;
    const int nt = (klen == 1) ? (T_ / 64) : ((klen + 63) >> 6);

    gl_lds16(gK[0], &KS[0][cs[0]]);
    gl_lds16(gK[1], &KS[0][cs[1]]);
    gl_lds16(gV[0], &VtS[0][cs[0]]);
    gl_lds16(gV[1], &VtS[0][cs[1]]);
    gl_lds16(gK[0] + 65536, &KS[1][cs[0]]);
    gl_lds16(gK[1] + 65536, &KS[1][cs[1]]);
    gl_lds16(gV[0] + 64,    &VtS[1][cs[0]]);
    gl_lds16(gV[1] + 64,    &VtS[1][cs[1]]);

    for (int kb = 0; kb < nt; ++kb) {
        const int cur = kb & 1;
        const int kbase = kb * 64;
        if (kb + 1 < nt) asm volatile("s_waitcnt vmcnt(4)" ::: "memory");
        else             asm volatile("s_waitcnt vmcnt(0)" ::: "memory");
        __builtin_amdgcn_s_barrier();
        __builtin_amdgcn_sched_barrier(0);

        float v[4][4];
        __builtin_amdgcn_s_setprio(1);
        #pragma unroll
        for (int mf = 0; mf < 4; ++mf) {
            f32x4 s; s[0]=0.f; s[1]=0.f; s[2]=0.f; s[3]=0.f;
            f16x8 a0 = *(const f16x8*)&KS[cur][akoff[mf][0]];
            f16x8 a1 = *(const f16x8*)&KS[cur][akoff[mf][1]];
            s = __builtin_amdgcn_mfma_f32_16x16x32_f16(a0, qb[0], s, 0, 0, 0);
            s = __builtin_amdgcn_mfma_f32_16x16x32_f16(a1, qb[1], s, 0, 0, 0);
            #pragma unroll
            for (int r = 0; r < 4; ++r) {
                int gk = kbase + mf * 16 + kg * 4 + r;
                float x = s[r] * 0.125f;
                if (gk >= klen || gk == gq) x = NEG_;
                v[mf][r] = x;
            }
        }
        __builtin_amdgcn_s_setprio(0);
        float mt = -3.0e38f;
        #pragma unroll
        for (int mf = 0; mf < 4; ++mf)
            #pragma unroll
            for (int r = 0; r < 4; ++r) mt = fmaxf(mt, v[mf][r]);
        mt = fmaxf(mt, __shfl_xor(mt, 16));
        mt = fmaxf(mt, __shfl_xor(mt, 32));
        float mnew = fmaxf(m_run, mt);
        float fac = __expf(m_run - mnew);
        float sum = 0.f;
        #pragma unroll
        for (int mf = 0; mf < 4; ++mf) {
            ushort4 pb;
            pb.x = f2h(__expf(v[mf][0] - mnew));
            pb.y = f2h(__expf(v[mf][1] - mnew));
            pb.z = f2h(__expf(v[mf][2] - mnew));
            pb.w = f2h(__expf(v[mf][3] - mnew));
            sum += h2f(pb.x) + h2f(pb.y) + h2f(pb.z) + h2f(pb.w);
            *(ushort4*)&Pl[wq][rl * 72 + mf * 16 + kg * 4] = pb;
        }
        sum += __shfl_xor(sum, 16);
        sum += __shfl_xor(sum, 32);
        l_run = l_run * fac + sum;
        m_run = mnew;
        #pragma unroll
        for (int i = 0; i < 4; ++i) {
            o[i][0] *= fac; o[i][1] *= fac; o[i][2] *= fac; o[i][3] *= fac;
        }
        f16x8 bp0 = *(const f16x8*)&Pl[wq][rl * 72 + kg * 8];
        f16x8 bp1 = *(const f16x8*)&Pl[wq][rl * 72 + 32 + kg * 8];
        __builtin_amdgcn_s_setprio(1);
        #pragma unroll
        for (int dmf = 0; dmf < 4; ++dmf) {
            f16x8 a0 = *(const f16x8*)&VtS[cur][akoff[dmf][0]];
            f16x8 a1 = *(const f16x8*)&VtS[cur][akoff[dmf][1]];
            o[dmf] = __builtin_amdgcn_mfma_f32_16x16x32_f16(a0, bp0, o[dmf], 0, 0, 0);
            o[dmf] = __builtin_amdgcn_mfma_f32_16x16x32_f16(a1, bp1, o[dmf], 0, 0, 0);
        }
        __builtin_amdgcn_s_setprio(0);
        __builtin_amdgcn_s_barrier();
        __builtin_amdgcn_sched_barrier(0);
        if (kb + 2 < nt) {
            const size_t ko = (size_t)(kbase + 128) * 1024;
            gl_lds16(gK[0] + ko, &KS[cur][cs[0]]);
            gl_lds16(gK[1] + ko, &KS[cur][cs[1]]);
            gl_lds16(gV[0] + kbase + 128, &VtS[cur][cs[0]]);
            gl_lds16(gV[1] + kbase + 128, &VtS[cur][cs[1]]);
        }
    }

    float invl = (gq < qlen) ? (1.f / l_run) : 0.f;
    #pragma unroll
    for (int dmf = 0; dmf < 4; ++dmf)
        #pragma unroll
        for (int r = 0; r < 4; ++r) {
            int dh = dmf * 16 + kg * 4 + r;
            size_t a = (size_t)(b * 1024 + gq) * 1024 + h * 64 + dh;
            q16[a] = f2h(o[dmf][r] * invl + h2f(q16[a]));
        }
}

// ======== FFN1: 256x256 8-wave interleaved-phase GEMM + relu-colsum ========
__global__ __launch_bounds__(512, 2) void ffn1_8p(
    const unsigned short* __restrict__ A,
    const unsigned short* __restrict__ B,
    float* __restrict__ hpart)
{
    __shared__ __align__(16) unsigned short As[2][16384];
    __shared__ __align__(16) unsigned short Bs[2][16384];
    __shared__ float hp[8][64];
    const int tid = threadIdx.x;
    const int m0 = blockIdx.y << 8, n0 = blockIdx.x << 8;
    const int lane = tid & 63, wave = tid >> 6;
    const int wm = wave >> 2, wn = wave & 3;
    const int rl = lane & 15, kg = lane >> 4, rl7 = lane & 7;

    const int row0 = tid >> 3;
    const int k8c = (tid & 7) ^ (row0 & 7);
    const int cs0 = tid * 8;
    const int gofs = row0 * 1024 + k8c * 8;
    const unsigned short* Ap = A + (size_t)m0 * 1024 + gofs;
    const unsigned short* Bp = B + (size_t)n0 * 1024 + gofs;

    const int base_a = ((wm * 128 + rl) * 8 + (kg ^ rl7)) * 8;
    const int base_b = (((wn >> 1) * 128 + (wn & 1) * 64 + rl) * 8 + (kg ^ rl7)) * 8;

    f32x4 acc[8][4];
    #pragma unroll
    for (int i = 0; i < 8; ++i)
        #pragma unroll
        for (int j = 0; j < 4; ++j) {
            acc[i][j][0] = 0.f; acc[i][j][1] = 0.f;
            acc[i][j][2] = 0.f; acc[i][j][3] = 0.f;
        }

    const int NT = 16;
    #pragma unroll
    for (int i = 0; i < 4; ++i) gl_lds16(Ap + i * 65536, &As[0][cs0 + i * 4096]);
    #pragma unroll
    for (int i = 0; i < 4; ++i) gl_lds16(Bp + i * 65536, &Bs[0][cs0 + i * 4096]);
    #pragma unroll
    for (int i = 0; i < 4; ++i) gl_lds16(Ap + i * 65536 + 64, &As[1][cs0 + i * 4096]);
    #pragma unroll
    for (int i = 0; i < 4; ++i) gl_lds16(Bp + i * 65536 + 64, &Bs[1][cs0 + i * 4096]);

    for (int t = 0; t < NT; ++t) {
        const int cur = t & 1;
        if (t + 1 < NT) asm volatile("s_waitcnt vmcnt(8)" ::: "memory");
        else            asm volatile("s_waitcnt vmcnt(0)" ::: "memory");
        __builtin_amdgcn_s_barrier();
        __builtin_amdgcn_sched_barrier(0);
        f16x8 av[8][2], bv[4][2];
        #pragma unroll
        for (int f = 0; f < 8; ++f) {
            int o = base_a + f * 1024;
            av[f][0] = *(const f16x8*)&As[cur][o];
            av[f][1] = *(const f16x8*)&As[cur][o ^ 32];
        }
        #pragma unroll
        for (int fn = 0; fn < 4; ++fn) {
            int o = base_b + fn * 1024;
            bv[fn][0] = *(const f16x8*)&Bs[cur][o];
            bv[fn][1] = *(const f16x8*)&Bs[cur][o ^ 32];
        }
        asm volatile("s_waitcnt lgkmcnt(0)" ::: "memory");
        __builtin_amdgcn_sched_barrier(0);
        __builtin_amdgcn_s_barrier();
        __builtin_amdgcn_sched_barrier(0);
        const bool pre = (t + 2 < NT);
        const int ko = (t + 2) << 6;
        #pragma unroll
        for (int p = 0; p < 4; ++p) {
            if (pre) {
                if (p < 2) {
                    gl_lds16(Ap + (2*p) * 65536 + ko,     &As[cur][cs0 + (2*p) * 4096]);
                    gl_lds16(Ap + (2*p + 1) * 65536 + ko, &As[cur][cs0 + (2*p + 1) * 4096]);
                } else {
                    gl_lds16(Bp + (2*p - 4) * 65536 + ko, &Bs[cur][cs0 + (2*p - 4) * 4096]);
                    gl_lds16(Bp + (2*p - 3) * 65536 + ko, &Bs[cur][cs0 + (2*p - 3) * 4096]);
                }
            }
            __builtin_amdgcn_sched_barrier(0);
            __builtin_amdgcn_s_setprio(1);
            #pragma unroll
            for (int f = 2 * p; f < 2 * p + 2; ++f)
                #pragma unroll
                for (int fn = 0; fn < 4; ++fn) {
                    acc[f][fn] = __builtin_amdgcn_mfma_f32_16x16x32_f16(av[f][0], bv[fn][0], acc[f][fn], 0, 0, 0);
                    acc[f][fn] = __builtin_amdgcn_mfma_f32_16x16x32_f16(av[f][1], bv[fn][1], acc[f][fn], 0, 0, 0);
                }
            __builtin_amdgcn_s_setprio(0);
            __builtin_amdgcn_sched_barrier(0);
        }
    }

    #pragma unroll
    for (int fn = 0; fn < 4; ++fn) {
        float p = 0.f;
        #pragma unroll
        for (int f = 0; f < 8; ++f)
            #pragma unroll
            for (int r = 0; r < 4; ++r) p += fmaxf(acc[f][fn][r], 0.f);
        p += __shfl_xor(p, 16);
        p += __shfl_xor(p, 32);
        if (kg == 0) hp[wave][fn * 16 + rl] = p;
    }
    __syncthreads();
    if (tid < 256) {
        int wn2 = tid >> 6, cc = tid & 63;
        float s = hp[wn2][cc] + hp[wn2 + 4][cc];
        hpart[(size_t)blockIdx.y * 4096 + n0 + wn2 * 64 + cc] = s;
    }
}

// ======== tail: mean16 (y==32) + final_partial (y<32), one dispatch ========
__global__ __launch_bounds__(256) void tail(const unsigned short* __restrict__ q16,
                                            const float* __restrict__ Hpart,
                                            const float* __restrict__ fw2,
                                            float* __restrict__ Pout,
                                            float* __restrict__ Mres)
{
    int tid = threadIdx.x;
    if (blockIdx.y == 32) {
        __shared__ float red[4][256];
        int b = blockIdx.x >> 2;
        int dbase = (blockIdx.x & 3) * 256;
        int tq = tid >> 6, dd = tid & 63;
        int d = dbase + dd * 4;
        const unsigned short* p = q16 + ((size_t)b * T_ + tq * 256) * 1024 + d;
        float s0 = 0.f, s1 = 0.f, s2 = 0.f, s3 = 0.f;
        for (int t = 0; t < 256; ++t) {
            ushort4 v = *(const ushort4*)(p + (size_t)t * 1024);
            s0 += h2f(v.x); s1 += h2f(v.y); s2 += h2f(v.z); s3 += h2f(v.w);
        }
        red[tq][dd*4] = s0; red[tq][dd*4+1] = s1; red[tq][dd*4+2] = s2; red[tq][dd*4+3] = s3;
        __syncthreads();
        if (tq == 0) {
            #pragma unroll
            for (int j = 0; j < 4; ++j) {
                float a = red[0][dd*4+j] + red[1][dd*4+j] + red[2][dd*4+j] + red[3][dd*4+j];
                Mres[(size_t)b * 1024 + d + j] = a * (1.f/1024.f);
            }
        }
        return;
    }
    __shared__ float red[4][4][64];
    __shared__ float hm[4][128];
    #pragma unroll
    for (int s = 0; s < 2; ++s) {
        int idx = s * 256 + tid;
        int bb = idx >> 7, jl = idx & 127;
        int j = blockIdx.y * 128 + jl;
        float acc = 0.f;
        #pragma unroll
        for (int i = 0; i < 4; ++i)
            acc += Hpart[((size_t)(bb * 4 + i)) * 4096 + j];
        hm[bb][jl] = acc * (1.f / 1024.f);
    }
    __syncthreads();
    int dd = tid & 63;
    int d = blockIdx.x * 64 + dd;
    int jq = tid >> 6;
    float s4[4] = {0.f, 0.f, 0.f, 0.f};
    for (int jj = 0; jj < 32; ++jj) {
        int jl = jq * 32 + jj;
        int j = blockIdx.y * 128 + jl;
        float wv = fw2[(size_t)j * 1024 + d];
        s4[0] += hm[0][jl] * wv;
        s4[1] += hm[1][jl] * wv;
        s4[2] += hm[2][jl] * wv;
        s4[3] += hm[3][jl] * wv;
    }
    #pragma unroll
    for (int bb = 0; bb < 4; ++bb) red[jq][bb][dd] = s4[bb];
    __syncthreads();
    if (jq == 0) {
        #pragma unroll
        for (int bb = 0; bb < 4; ++bb) {
            float tot = red[0][bb][dd] + red[1][bb][dd] + red[2][bb][dd] + red[3][bb][dd];
            Pout[((size_t)blockIdx.y * 4 + bb) * 1024 + d] = tot;
        }
    }
}

// ---------------- out[b][d] = Mres[b][d] + sum_{jy<32} Pout[jy][b][d] ----------------
__global__ __launch_bounds__(256) void reduce_out(const float* __restrict__ Mres,
                                                  const float* __restrict__ Pout,
                                                  float* __restrict__ out)
{
    int idx = blockIdx.x * 256 + threadIdx.x;
    int b = idx >> 10, d = idx & 1023;
    float s = Mres[(size_t)b * 1024 + d];
    #pragma unroll
    for (int jy = 0; jy < 32; ++jy)
        s += Pout[((size_t)jy * 4 + b) * 1024 + d];
    out[(size_t)b * 1024 + d] = s;
}

extern "C" void kernel_launch(void* const* d_in, const int* in_sizes, int n_in,
                              void* d_out, int out_size, void* d_ws, size_t ws_size,
                              hipStream_t stream)
{
    const float* queries = (const float*)d_in[0];
    const int*   qlens   = (const int*)d_in[2];
    const int*   klens   = (const int*)d_in[3];
    const float* pe_q    = (const float*)d_in[4];
    const float* pe_k    = (const float*)d_in[5];
    const float* Wq      = (const float*)d_in[6];
    const float* Wk      = (const float*)d_in[7];
    const float* Wv      = (const float*)d_in[8];
    const float* fw1     = (const float*)d_in[9];
    const float* fw2     = (const float*)d_in[10];
    float* out = (float*)d_out;

    char* w = (char*)d_ws;
    unsigned short* Qh   = (unsigned short*)(w);                  // [0,8)
    unsigned short* A2   = (unsigned short*)(w + (8ll  << 20));   // [8,24)
    unsigned short* q16  = A2;                                    // [8,16)
    unsigned short* Kh16 = (unsigned short*)(w + (24ll << 20));   // [24,32)
    unsigned short* B2   = (unsigned short*)(w + (32ll << 20));   // [32,36)
    unsigned short* WvT  = (unsigned short*)(w + (36ll << 20));   // [36,38)
    unsigned short* Vt   = (unsigned short*)(w + (38ll << 20));   // [38,46)
    unsigned short* fw1T = (unsigned short*)(w + (46ll << 20));   // [46,54)
    float*          Hpart= (float*)(w + (54ll << 20));            // 256 KB
    float*          Mres = (float*)(w + (55ll << 20));            // 16 KB
    float*          Pout = (float*)(w + (56ll << 20));            // 512 KB

    // 1) all conversions, one launch
    conv_all<<<15360, 256, 0, stream>>>(queries, pe_q, pe_k, Wq, Wk, Wv, fw1, klens,
                                        A2, B2, WvT, fw1T);
    // 2) stacked [Q|K] GEMM, 128x128 2-phase (proven; fills all CUs), 128-gran len-skip
    qk_2p<<<dim3(16, 64), 256, 0, stream>>>(A2, B2, Qh, Kh16, qlens, klens);
    // 3) V = Kh16 @ Wv, fp16 transposed Vt[b,h][dh][t]
    gemm_v<<<dim3(8, 64), 256, 0, stream>>>(Kh16, WvT, Vt, klens);
    // 4) MFMA attention + residual -> q16 in place
    attn_mfma<<<1024, 256, 0, stream>>>(Qh, Kh16, Vt, q16, qlens, klens);
    // 5) FFN1: 256x256 8-wave interleaved schedule, fused relu-colsum
    ffn1_8p<<<dim3(16, 16), 512, 0, stream>>>(q16, fw1T, Hpart);
    // 6) tail: mean_t(res) + FFN2 partials, one dispatch
    tail<<<dim3(16, 33), 256, 0, stream>>>(q16, Hpart, fw2, Pout, Mres);
    reduce_out<<<16, 256, 0, stream>>>(Mres, Pout, out);
}